// Round 3
// baseline (133.318 us; speedup 1.0000x reference)
//
#include <hip/hip_runtime.h>
#include <math.h>

#define BB 1024
#define TT 1024
#define HH 256
#define CC 10

// State fold: track r where h = 1 - 2r.
//   z = wd*h + win*x + bh,  m = S*z  (S = 2*log2e)
//   m = A*r + q,  A = -2*wd*S,  q = fma(x, win*S, (bh + wd)*S)
//   t = exp2(m); r' = 1/(t+1)
//
// Round-3: replace v_rcp_f32 (trans pipe) with integer-magic + 3 Newton
// iterations (main VALU pipe). Theory: kernel is trans-pipe bound at
// 1/8 rate; halving trans ops (only exp2 remains) should cut the floor.
// u = t+1 in [1, 2^103] with this data: no inf/NaN path for the magic seed.
// m -> -inf  =>  t=0, u=1, r=1 (h=-1)  — saturation preserved.

typedef float f2 __attribute__((ext_vector_type(2)));

__global__ __launch_bounds__(HH) void vanilla_rnn_kernel(
    const float* __restrict__ x,
    const float* __restrict__ W_hx,
    const float* __restrict__ W_hh,
    const float* __restrict__ b_h,
    const float* __restrict__ W_hp,
    const float* __restrict__ b_o,
    float* __restrict__ out)
{
    __shared__ float xs0[TT + 8];   // +2 float4 pad for prefetch tail
    __shared__ float xs1[TT + 8];
    __shared__ float part[2][CC * 4];

    const int tid = threadIdx.x;   // h index
    const int b0  = blockIdx.x * 2;

    // Stage both x rows (2 x 4 KB) into LDS: 256 threads x float4 each.
    ((float4*)xs0)[tid] = ((const float4*)(x + (size_t)b0 * TT))[tid];
    ((float4*)xs1)[tid] = ((const float4*)(x + (size_t)(b0 + 1) * TT))[tid];
    if (tid < 2) {
        ((float4*)xs0)[TT / 4 + tid] = make_float4(0.f, 0.f, 0.f, 0.f);
        ((float4*)xs1)[TT / 4 + tid] = make_float4(0.f, 0.f, 0.f, 0.f);
    }

    // Per-h constants (pre-scaled by S = 2*log2(e)) — shared by both chains.
    const float S    = 2.88539008177792681472f;
    const float winS = W_hx[tid] * S;
    const float wd   = W_hh[tid * HH + tid];
    const float A    = -2.0f * wd * S;
    const float bhS2 = (b_h[tid] + wd) * S;
    float whp[CC];
#pragma unroll
    for (int c = 0; c < CC; ++c) whp[c] = W_hp[c * HH + tid];

    __syncthreads();

    // Two serial recurrences over t, interleaved; distance-2 LDS prefetch.
    f2 r = (f2){0.5f, 0.5f};              // h0 = 0  =>  r0 = 0.5
    const f2 A2   = (f2){A, A};
    const f2 one2 = (f2){1.0f, 1.0f};
    const f2 two2 = (f2){2.0f, 2.0f};

    const float4* xa = (const float4*)xs0;
    const float4* xb = (const float4*)xs1;
    float4 curA = xa[0], nxtA = xa[1];
    float4 curB = xb[0], nxtB = xb[1];
#pragma unroll 4
    for (int t4 = 0; t4 < TT / 4; ++t4) {
        float4 pfA = xa[t4 + 2];          // lands in pad on last two iters
        float4 pfB = xb[t4 + 2];

        f2 q, m, t, u, y, e;
#define STEP(XA, XB)                                            \
        q.x = fmaf((XA), winS, bhS2);                           \
        q.y = fmaf((XB), winS, bhS2);                           \
        m   = __builtin_elementwise_fma(A2, r, q);              \
        t.x = __builtin_amdgcn_exp2f(m.x);                      \
        t.y = __builtin_amdgcn_exp2f(m.y);                      \
        u   = t + one2;                                         \
        y.x = __uint_as_float(0x7EF311C3u - __float_as_uint(u.x)); \
        y.y = __uint_as_float(0x7EF311C3u - __float_as_uint(u.y)); \
        e   = __builtin_elementwise_fma(-u, y, two2); y = y * e;   \
        e   = __builtin_elementwise_fma(-u, y, two2); y = y * e;   \
        e   = __builtin_elementwise_fma(-u, y, two2); r = y * e;

        STEP(curA.x, curB.x)
        STEP(curA.y, curB.y)
        STEP(curA.z, curB.z)
        STEP(curA.w, curB.w)
#undef STEP

        curA = nxtA; curB = nxtB;
        nxtA = pfA;  nxtB = pfB;
    }
    float h0 = fmaf(-2.0f, r.x, 1.0f);
    float h1 = fmaf(-2.0f, r.y, 1.0f);

    // Projection: out[b,c] = sum_h h * W_hp[c,h] + b_o[c]  (both rows)
    const int lane = tid & 63;
    const int wave = tid >> 6;
#pragma unroll
    for (int c = 0; c < CC; ++c) {
        float v0 = h0 * whp[c];
        float v1 = h1 * whp[c];
#pragma unroll
        for (int off = 32; off >= 1; off >>= 1) {
            v0 += __shfl_down(v0, off);
            v1 += __shfl_down(v1, off);
        }
        if (lane == 0) { part[0][c * 4 + wave] = v0; part[1][c * 4 + wave] = v1; }
    }
    __syncthreads();

    if (tid < 2 * CC) {
        const int bb = tid / CC;      // 0 or 1: which batch row
        const int c  = tid - bb * CC;
        float acc = b_o[c];
#pragma unroll
        for (int w = 0; w < 4; ++w) acc += part[bb][c * 4 + w];
        out[(size_t)(b0 + bb) * CC + c] = acc;
    }
}

extern "C" void kernel_launch(void* const* d_in, const int* in_sizes, int n_in,
                              void* d_out, int out_size, void* d_ws, size_t ws_size,
                              hipStream_t stream) {
    const float* x    = (const float*)d_in[0];
    const float* W_hx = (const float*)d_in[1];
    const float* W_hh = (const float*)d_in[2];
    const float* b_h  = (const float*)d_in[3];
    const float* W_hp = (const float*)d_in[4];
    const float* b_o  = (const float*)d_in[5];
    float* out = (float*)d_out;

    vanilla_rnn_kernel<<<BB / 2, HH, 0, stream>>>(x, W_hx, W_hh, b_h, W_hp, b_o, out);
}

// Round 4
// 125.148 us; speedup vs baseline: 1.0653x; 1.0653x over previous
//
#include <hip/hip_runtime.h>
#include <math.h>

#define BB 1024
#define TT 1024
#define HH 256
#define CC 10
#define RB 4    // batch rows (chains) per block -> ILP-4 per lane, 1 wave/SIMD

// State fold: track r where h = 1 - 2r.
//   z = wd*h + win*x + bh,  m = S*z  (S = 2*log2e)
//   m = A*r + q,  A = -2*wd*S,  q = fma(x, win*S, (bh + wd)*S)
//   t = exp2(m); r' = rcp(t + 1)
// Loop-carried chain: fma -> exp2 -> add -> rcp (4 ops), per chain.
//
// Round-4: all 4 chains of a SIMD live in ONE wave as 4-deep ILP so the
// compiler statically interleaves them around the trans-op latency
// (rounds 0/1 showed dynamic wave arbitration never dovetails lockstep
// waves: wall 145 cy/step vs 88 cy issue floor). Ping-pong register sets
// (va/vb) with direct LDS loads kill the float4 rotation movs (~16 cy/step
// of measured VALU busy). Grid 256 = 1 block/CU, 4 waves/block.

__global__ __launch_bounds__(HH, 1) void vanilla_rnn_kernel(
    const float* __restrict__ x,
    const float* __restrict__ W_hx,
    const float* __restrict__ W_hh,
    const float* __restrict__ b_h,
    const float* __restrict__ W_hp,
    const float* __restrict__ b_o,
    float* __restrict__ out)
{
    __shared__ float xs[RB][TT + 8];     // +2 float4 pad: prefetch tail lands here
    __shared__ float part[RB][CC * 4];

    const int tid = threadIdx.x;   // h index
    const int b0  = blockIdx.x * RB;

    // Stage RB x-rows (4 x 4 KB) into LDS: 256 threads x float4 per row.
#pragma unroll
    for (int rr = 0; rr < RB; ++rr) {
        ((float4*)xs[rr])[tid] = ((const float4*)(x + (size_t)(b0 + rr) * TT))[tid];
        if (tid < 2) ((float4*)xs[rr])[TT / 4 + tid] = make_float4(0.f, 0.f, 0.f, 0.f);
    }

    // Per-h constants (pre-scaled by S = 2*log2(e)) — shared by all 4 chains.
    const float S    = 2.88539008177792681472f;
    const float winS = W_hx[tid] * S;
    const float wd   = W_hh[tid * HH + tid];
    const float A    = -2.0f * wd * S;
    const float bhS2 = (b_h[tid] + wd) * S;
    float whp[CC];
#pragma unroll
    for (int c = 0; c < CC; ++c) whp[c] = W_hp[c * HH + tid];

    __syncthreads();

    const float4* x0 = (const float4*)xs[0];
    const float4* x1 = (const float4*)xs[1];
    const float4* x2 = (const float4*)xs[2];
    const float4* x3 = (const float4*)xs[3];

    float r0 = 0.5f, r1 = 0.5f, r2 = 0.5f, r3 = 0.5f;   // h0=0 => r=0.5

#define STEP4(E0, E1, E2, E3) {                         \
        float q0 = fmaf((E0), winS, bhS2);              \
        float q1 = fmaf((E1), winS, bhS2);              \
        float q2 = fmaf((E2), winS, bhS2);              \
        float q3 = fmaf((E3), winS, bhS2);              \
        float m0 = fmaf(A, r0, q0);                     \
        float m1 = fmaf(A, r1, q1);                     \
        float m2 = fmaf(A, r2, q2);                     \
        float m3 = fmaf(A, r3, q3);                     \
        float t0 = __builtin_amdgcn_exp2f(m0);          \
        float t1 = __builtin_amdgcn_exp2f(m1);          \
        float t2 = __builtin_amdgcn_exp2f(m2);          \
        float t3 = __builtin_amdgcn_exp2f(m3);          \
        r0 = __builtin_amdgcn_rcpf(t0 + 1.0f);          \
        r1 = __builtin_amdgcn_rcpf(t1 + 1.0f);          \
        r2 = __builtin_amdgcn_rcpf(t2 + 1.0f);          \
        r3 = __builtin_amdgcn_rcpf(t3 + 1.0f); }

    // Ping-pong register sets, i += 2: loads land directly in va*/vb* —
    // no rotation movs. Prefetch distance = one 4-step block (~90 cy issue),
    // tail reads land in the zero pad.
    float4 va0 = x0[0], va1 = x1[0], va2 = x2[0], va3 = x3[0];
    for (int i = 0; i < TT / 4; i += 2) {
        float4 vb0 = x0[i + 1], vb1 = x1[i + 1], vb2 = x2[i + 1], vb3 = x3[i + 1];
        STEP4(va0.x, va1.x, va2.x, va3.x)
        STEP4(va0.y, va1.y, va2.y, va3.y)
        STEP4(va0.z, va1.z, va2.z, va3.z)
        STEP4(va0.w, va1.w, va2.w, va3.w)
        va0 = x0[i + 2]; va1 = x1[i + 2]; va2 = x2[i + 2]; va3 = x3[i + 2];
        STEP4(vb0.x, vb1.x, vb2.x, vb3.x)
        STEP4(vb0.y, vb1.y, vb2.y, vb3.y)
        STEP4(vb0.z, vb1.z, vb2.z, vb3.z)
        STEP4(vb0.w, vb1.w, vb2.w, vb3.w)
    }
#undef STEP4

    const float h0 = fmaf(-2.0f, r0, 1.0f);
    const float h1 = fmaf(-2.0f, r1, 1.0f);
    const float h2 = fmaf(-2.0f, r2, 1.0f);
    const float h3 = fmaf(-2.0f, r3, 1.0f);

    // Projection: out[b,c] = sum_h h * W_hp[c,h] + b_o[c]  (all 4 rows)
    const int lane = tid & 63;
    const int wave = tid >> 6;
#pragma unroll
    for (int c = 0; c < CC; ++c) {
        float v0 = h0 * whp[c];
        float v1 = h1 * whp[c];
        float v2 = h2 * whp[c];
        float v3 = h3 * whp[c];
#pragma unroll
        for (int off = 32; off >= 1; off >>= 1) {
            v0 += __shfl_down(v0, off);
            v1 += __shfl_down(v1, off);
            v2 += __shfl_down(v2, off);
            v3 += __shfl_down(v3, off);
        }
        if (lane == 0) {
            part[0][c * 4 + wave] = v0;
            part[1][c * 4 + wave] = v1;
            part[2][c * 4 + wave] = v2;
            part[3][c * 4 + wave] = v3;
        }
    }
    __syncthreads();

    if (tid < RB * CC) {
        const int bb = tid / CC;      // which batch row
        const int c  = tid - bb * CC;
        float acc = b_o[c];
#pragma unroll
        for (int w = 0; w < 4; ++w) acc += part[bb][c * 4 + w];
        out[(size_t)(b0 + bb) * CC + c] = acc;
    }
}

extern "C" void kernel_launch(void* const* d_in, const int* in_sizes, int n_in,
                              void* d_out, int out_size, void* d_ws, size_t ws_size,
                              hipStream_t stream) {
    const float* x    = (const float*)d_in[0];
    const float* W_hx = (const float*)d_in[1];
    const float* W_hh = (const float*)d_in[2];
    const float* b_h  = (const float*)d_in[3];
    const float* W_hp = (const float*)d_in[4];
    const float* b_o  = (const float*)d_in[5];
    float* out = (float*)d_out;

    vanilla_rnn_kernel<<<BB / RB, HH, 0, stream>>>(x, W_hx, W_hh, b_h, W_hp, b_o, out);
}

// Round 6
// 110.500 us; speedup vs baseline: 1.2065x; 1.1326x over previous
//
#include <hip/hip_runtime.h>
#include <math.h>

#define BB 1024
#define TT 1024
#define HH 256
#define CC 10

// State fold: track r where h = 1 - 2r.
//   z = wd*h + win*x + bh,  m = S*z  (S = 2*log2e)
//   m = A*r + q,  A = -2*wd*S,  q = fma(x, win*S, (bh + wd)*S)
//   t = exp2(m); r' = rcp(t + 1)
// Loop-carried chain: fma -> exp2 -> add -> rcp (4 ops), per chain.
//
// Round-6 = round-5 resubmitted (bench infra failed; kernel never ran).
// Keep the proven 2-waves/SIMD x ILP-2 shape (rounds 0/1/4 mapped the
// shape space; this tied for best). Shrink the ISSUE component:
//  - pair the two chains' q-fma / chain-fma / +1-add into v_pk_fma_f32 /
//    v_pk_add_f32 (full-rate dual-f32 VOP3P): 44 -> 38 cy per wave-step.
//  - x rows staged INTERLEAVED in LDS ({A_t,B_t} pairs) so the pk operand
//    comes straight out of a ds_read_b128 half — no pair-assembly VALU.
//  - round-4's ping-pong named-register loads: zero rotation movs.
// exp2/rcp arithmetic identical to the 62us baseline (absmax ~4e-6).

typedef float f2 __attribute__((ext_vector_type(2)));
typedef float f4 __attribute__((ext_vector_type(4)));

__global__ __launch_bounds__(HH) void vanilla_rnn_kernel(
    const float* __restrict__ x,
    const float* __restrict__ W_hx,
    const float* __restrict__ W_hh,
    const float* __restrict__ b_h,
    const float* __restrict__ W_hp,
    const float* __restrict__ b_o,
    float* __restrict__ out)
{
    __shared__ f4 xsp[TT / 2 + 2];        // interleaved pairs {A,B,A,B}; +2 f4 pad
    __shared__ float part[2][CC * 4];

    const int tid = threadIdx.x;   // h index
    const int b0  = blockIdx.x * 2;

    // Stage both rows interleaved: xsp[k] = {A(2k), B(2k), A(2k+1), B(2k+1)}.
    {
        f4 a4 = ((const f4*)(x + (size_t)b0 * TT))[tid];
        f4 b4 = ((const f4*)(x + (size_t)(b0 + 1) * TT))[tid];
        xsp[2 * tid]     = (f4){a4.x, b4.x, a4.y, b4.y};
        xsp[2 * tid + 1] = (f4){a4.z, b4.z, a4.w, b4.w};
        if (tid < 2) xsp[TT / 2 + tid] = (f4){0.f, 0.f, 0.f, 0.f};
    }

    // Per-h constants (pre-scaled by S = 2*log2(e)) — shared by both chains.
    const float S    = 2.88539008177792681472f;
    const float winS = W_hx[tid] * S;
    const float wd   = W_hh[tid * HH + tid];
    const float bhS2 = (b_h[tid] + wd) * S;
    const f2 A2   = (f2){-2.0f * wd * S, -2.0f * wd * S};
    const f2 win2 = (f2){winS, winS};
    const f2 bh2  = (f2){bhS2, bhS2};
    const f2 one2 = (f2){1.0f, 1.0f};
    float whp[CC];
#pragma unroll
    for (int c = 0; c < CC; ++c) whp[c] = W_hp[c * HH + tid];

    __syncthreads();

    f2 r = (f2){0.5f, 0.5f};              // h0 = 0  =>  r = 0.5

#define STEP(XPAIR) {                                   \
        f2 xv = (XPAIR);                                \
        f2 q  = __builtin_elementwise_fma(xv, win2, bh2); \
        f2 m  = __builtin_elementwise_fma(A2, r, q);    \
        f2 t;                                           \
        t.x = __builtin_amdgcn_exp2f(m.x);              \
        t.y = __builtin_amdgcn_exp2f(m.y);              \
        f2 u = t + one2;                                \
        r.x = __builtin_amdgcn_rcpf(u.x);               \
        r.y = __builtin_amdgcn_rcpf(u.y); }

    // Ping-pong named registers, k += 4 (8 time-steps per iter), loads land
    // directly in va/vb/vc/vd — no rotation movs. Prefetch distance = 4
    // steps (~150 cy issue) >= LDS latency; tail loads land in the pad.
    f4 va = xsp[0], vb = xsp[1];
    for (int k = 0; k < TT / 2; k += 4) {
        f4 vc = xsp[k + 2], vd = xsp[k + 3];
        STEP(va.xy) STEP(va.zw) STEP(vb.xy) STEP(vb.zw)
        va = xsp[k + 4]; vb = xsp[k + 5];   // last iter: reads the zero pad
        STEP(vc.xy) STEP(vc.zw) STEP(vd.xy) STEP(vd.zw)
    }
#undef STEP

    const float h0 = fmaf(-2.0f, r.x, 1.0f);
    const float h1 = fmaf(-2.0f, r.y, 1.0f);

    // Projection: out[b,c] = sum_h h * W_hp[c,h] + b_o[c]  (both rows)
    const int lane = tid & 63;
    const int wave = tid >> 6;
#pragma unroll
    for (int c = 0; c < CC; ++c) {
        float v0 = h0 * whp[c];
        float v1 = h1 * whp[c];
#pragma unroll
        for (int off = 32; off >= 1; off >>= 1) {
            v0 += __shfl_down(v0, off);
            v1 += __shfl_down(v1, off);
        }
        if (lane == 0) { part[0][c * 4 + wave] = v0; part[1][c * 4 + wave] = v1; }
    }
    __syncthreads();

    if (tid < 2 * CC) {
        const int bb = tid / CC;      // 0 or 1: which batch row
        const int c  = tid - bb * CC;
        float acc = b_o[c];
#pragma unroll
        for (int w = 0; w < 4; ++w) acc += part[bb][c * 4 + w];
        out[(size_t)(b0 + bb) * CC + c] = acc;
    }
}

extern "C" void kernel_launch(void* const* d_in, const int* in_sizes, int n_in,
                              void* d_out, int out_size, void* d_ws, size_t ws_size,
                              hipStream_t stream) {
    const float* x    = (const float*)d_in[0];
    const float* W_hx = (const float*)d_in[1];
    const float* W_hh = (const float*)d_in[2];
    const float* b_h  = (const float*)d_in[3];
    const float* W_hp = (const float*)d_in[4];
    const float* b_o  = (const float*)d_in[5];
    float* out = (float*)d_out;

    vanilla_rnn_kernel<<<BB / 2, HH, 0, stream>>>(x, W_hx, W_hh, b_h, W_hp, b_o, out);
}